// Round 3
// baseline (568.158 us; speedup 1.0000x reference)
//
#include <hip/hip_runtime.h>
#include <hip/hip_bf16.h>

#define BATCH   2048
#define DIM     512
#define DB_N    50000
#define TOPK    5
#define PADN    50176       // 196 tiles of 256
#define NTT     196         // total db tiles
#define NCHUNK  32
#define TM      256         // batch rows per block tile
#define TN      256         // db rows per tile
#define KB      64          // K per staging step (8 steps over DIM=512)

typedef float  f32x4  __attribute__((ext_vector_type(4)));
typedef short  bf16x8 __attribute__((ext_vector_type(8)));

__device__ __forceinline__ short f2bf(float f) {
    union { float f; unsigned u; } v; v.f = f;
    unsigned r = v.u + 0x7FFFu + ((v.u >> 16) & 1u);   // RNE
    return (short)(r >> 16);
}

__device__ __forceinline__ bf16x8 pack8(float4 a, float4 b) {
    bf16x8 r;
    r[0] = f2bf(a.x); r[1] = f2bf(a.y); r[2] = f2bf(a.z); r[3] = f2bf(a.w);
    r[4] = f2bf(b.x); r[5] = f2bf(b.y); r[6] = f2bf(b.z); r[7] = f2bf(b.w);
    return r;
}

__device__ __forceinline__ void async16(const void* g, void* l) {
    __builtin_amdgcn_global_load_lds(
        (const __attribute__((address_space(1))) unsigned int*)g,
        (__attribute__((address_space(3))) unsigned int*)l, 16, 0, 0);
}

// ============ convert: normalize rows -> bf16, k-chunked, pre-swizzled ============
// dest[((kb*nrows + r)*8 + w)*8] holds row_norm[r][kb*64 + (w^(r&7))*8 .. +8]
// (so a linear global_load_lds of 2048 consecutive 16B units lands XOR-swizzled in LDS)
template<int NROWS>
__global__ void convert_kernel(const float* __restrict__ src, short* __restrict__ dst, int nreal) {
    const int r    = blockIdx.x * 4 + (threadIdx.x >> 6);
    const int lane = threadIdx.x & 63;
    bf16x8 u = {0,0,0,0,0,0,0,0};
    if (r < nreal) {
        const float* row = src + (size_t)r * DIM;
        const float4 a = *(const float4*)(row + lane * 8);
        const float4 b = *(const float4*)(row + lane * 8 + 4);
        float ss = a.x*a.x + a.y*a.y + a.z*a.z + a.w*a.w
                 + b.x*b.x + b.y*b.y + b.z*b.z + b.w*b.w;
        #pragma unroll
        for (int off = 1; off < 64; off <<= 1) ss += __shfl_xor(ss, off);
        const float inv = 1.0f / fmaxf(sqrtf(ss), 1e-12f);
        float4 an = {a.x*inv, a.y*inv, a.z*inv, a.w*inv};
        float4 bn = {b.x*inv, b.y*inv, b.z*inv, b.w*inv};
        u = pack8(an, bn);
    }
    const int kb = lane >> 3;
    const int w  = lane & 7;
    *(bf16x8*)(dst + ((size_t)kb * NROWS + r) * 64 + ((w ^ (r & 7)) << 3)) = u;
}

// ============ fused sim GEMM (256x256 tile, 8 waves, 8x4 frags) + running top-5 ============
__global__ __launch_bounds__(512, 2) void sim_topk_kernel(
    const short* __restrict__ hz, const short* __restrict__ dbz,
    unsigned* __restrict__ pc) {

    __shared__ __align__(16) short As[2][TM * 64];   // 2 x 32KB
    __shared__ __align__(16) short Bs[2][TN * 64];   // 2 x 32KB

    const int tid  = threadIdx.x;
    const int lane = tid & 63;
    const int wid  = tid >> 6;
    const int l15  = lane & 15;
    const int lhi  = lane >> 4;
    const int wm   = wid >> 2;            // 0..1 (M half)
    const int wn   = wid & 3;             // 0..3 (N quarter)
    const int rb   = blockIdx.x >> 5;     // 0..7 batch block
    const int mc   = blockIdx.x & 31;     // 0..31 chunk
    const int ts   = mc * 6 + (mc < 4 ? mc : 4);
    const int te   = ts + 6 + (mc < 4 ? 1 : 0);

    // per-lane top-5 state: lane owns 2 rows (slot s): mf=(s<<2)|(l15>>2), i=l15&3, its lhi
    float tv0[TOPK], tv1[TOPK]; int ti0[TOPK], ti1[TOPK];
    #pragma unroll
    for (int j = 0; j < TOPK; ++j) {
        tv0[j] = -3.0e38f; tv1[j] = -3.0e38f; ti0[j] = 0; ti1[j] = 0;
    }

    const short* abase = hz + ((size_t)rb * TM) * 64;   // + kb*2048*64
    const int    swz_base = l15 & 7;

    // staging: 2048 16B-units per tile (A and B each); 512 threads x 4 units
    auto STAGE = [&](int buf, int t, int kb) {
        const short* ab = abase + (size_t)kb * (2048 * 64);
        const short* bb = dbz + ((size_t)kb * PADN + t * TN) * 64;
        #pragma unroll
        for (int j = 0; j < 4; ++j) {
            const int u = tid + j * 512;
            async16(ab + (size_t)u * 8, &As[buf][u * 8]);
            async16(bb + (size_t)u * 8, &Bs[buf][u * 8]);
        }
    };

    f32x4 acc[8][4];

    STAGE(0, ts, 0);
    __syncthreads();

    int s = 0;
    for (int t = ts; t < te; ++t) {
        #pragma unroll
        for (int mf = 0; mf < 8; ++mf)
            #pragma unroll
            for (int nf = 0; nf < 4; ++nf) acc[mf][nf] = (f32x4){0.f, 0.f, 0.f, 0.f};

        #pragma unroll 1
        for (int kb = 0; kb < 8; ++kb) {
            // stage next step
            int nkb = kb + 1, nt = t;
            if (nkb == 8) { nkb = 0; nt = t + 1; }
            if (nt < te) STAGE((s + 1) & 1, nt, nkb);

            const int par = s & 1;
            #pragma unroll
            for (int ks = 0; ks < 2; ++ks) {
                const int swz = (((ks << 2) | lhi) ^ swz_base) << 3;
                bf16x8 af[8], bf[4];
                #pragma unroll
                for (int mf = 0; mf < 8; ++mf)
                    af[mf] = *(const bf16x8*)(&As[par][(wm * 128 + mf * 16 + l15) * 64 + swz]);
                #pragma unroll
                for (int nf = 0; nf < 4; ++nf)
                    bf[nf] = *(const bf16x8*)(&Bs[par][(wn * 64 + nf * 16 + l15) * 64 + swz]);
                #pragma unroll
                for (int mf = 0; mf < 8; ++mf)
                    #pragma unroll
                    for (int nf = 0; nf < 4; ++nf)
                        acc[mf][nf] = __builtin_amdgcn_mfma_f32_16x16x32_bf16(af[mf], bf[nf], acc[mf][nf], 0, 0, 0);
            }

            if (kb == 7) {
                // ================= per-tile top-5 epilogue (before barrier: overlaps staging) =================
                const int n0 = t * TN;
                // mask pad cols (only last tile has any)
                if (n0 + TN > DB_N) {
                    #pragma unroll
                    for (int nf = 0; nf < 4; ++nf) {
                        const bool valid = (n0 + wn * 64 + nf * 16 + l15) < DB_N;
                        #pragma unroll
                        for (int mf = 0; mf < 8; ++mf)
                            #pragma unroll
                            for (int i = 0; i < 4; ++i)
                                acc[mf][nf][i] = valid ? acc[mf][nf][i] : -3.0e38f;
                    }
                }
                #pragma unroll
                for (int mf = 0; mf < 8; ++mf) {
                    #pragma unroll
                    for (int i = 0; i < 4; ++i) {
                        // row for this (mf,i) in my lhi group; owner lane l15 = (mf&3)*4+i
                        const int osrc = (lane & 48) + ((mf & 3) << 2) + i;
                        float thr = __shfl((mf < 4) ? tv0[TOPK - 1] : tv1[TOPK - 1], osrc, 64);
                        float m = fmaxf(fmaxf(acc[mf][0][i], acc[mf][1][i]),
                                        fmaxf(acc[mf][2][i], acc[mf][3][i]));
                        if (__any(m > thr)) {
                            #pragma unroll 1
                            for (int it = 0; it < TOPK; ++it) {
                                float v = acc[mf][0][i]; int c = l15;
                                #pragma unroll
                                for (int nf = 1; nf < 4; ++nf) {
                                    const float v2 = acc[mf][nf][i];
                                    const int   c2 = nf * 16 + l15;
                                    if (v2 > v) { v = v2; c = c2; }
                                }
                                #pragma unroll
                                for (int sh = 1; sh < 16; sh <<= 1) {
                                    const float ov = __shfl_xor(v, sh);
                                    const int   oc = __shfl_xor(c, sh);
                                    if (ov > v || (ov == v && oc < c)) { v = ov; c = oc; }
                                }
                                if (!__any(v > thr)) break;
                                const int gi = n0 + wn * 64 + c;
                                const bool owner = (l15 == ((mf & 3) << 2) + i);
                                if (owner && v > thr) {
                                    if (mf < 4) {
                                        #pragma unroll
                                        for (int j = TOPK - 1; j >= 1; --j) {
                                            const bool gt  = v > tv0[j];
                                            const bool gtp = v > tv0[j - 1];
                                            tv0[j] = gt ? (gtp ? tv0[j - 1] : v)  : tv0[j];
                                            ti0[j] = gt ? (gtp ? ti0[j - 1] : gi) : ti0[j];
                                        }
                                        if (v > tv0[0]) { tv0[0] = v; ti0[0] = gi; }
                                    } else {
                                        #pragma unroll
                                        for (int j = TOPK - 1; j >= 1; --j) {
                                            const bool gt  = v > tv1[j];
                                            const bool gtp = v > tv1[j - 1];
                                            tv1[j] = gt ? (gtp ? tv1[j - 1] : v)  : tv1[j];
                                            ti1[j] = gt ? (gtp ? ti1[j - 1] : gi) : ti1[j];
                                        }
                                        if (v > tv1[0]) { tv1[0] = v; ti1[0] = gi; }
                                    }
                                }
                                // mask winner
                                #pragma unroll
                                for (int nf = 0; nf < 4; ++nf)
                                    if (nf * 16 + l15 == c) acc[mf][nf][i] = -3.0e38f;
                                // refresh threshold
                                thr = __shfl((mf < 4) ? tv0[TOPK - 1] : tv1[TOPK - 1], osrc, 64);
                            }
                        }
                    }
                }
            }
            __syncthreads();
            ++s;
        }
    }

    // ---- write packed per-(row, chunk) top-5: u32 = bf16(val)<<16 | idx
    #pragma unroll
    for (int slot = 0; slot < 2; ++slot) {
        const int mf  = (slot << 2) | (l15 >> 2);
        const int i   = l15 & 3;
        const int row = rb * TM + wm * 128 + mf * 16 + lhi * 4 + i;
        const size_t base = ((size_t)row * NCHUNK + mc) * TOPK;
        #pragma unroll
        for (int j = 0; j < TOPK; ++j) {
            const float v = slot ? tv1[j] : tv0[j];
            const int  ix = slot ? ti1[j] : ti0[j];
            pc[base + j] = (((unsigned)(unsigned short)f2bf(v)) << 16) | (unsigned)ix;
        }
    }
}

// ============ merge chunks (wave-parallel), softmax, gather, blend ============
__global__ void finalize_kernel(const float* __restrict__ h, const float* __restrict__ db,
                                const float* __restrict__ alpha_p,
                                const unsigned* __restrict__ pc,
                                float* __restrict__ out) {
    const int b   = blockIdx.x;
    const int tid = threadIdx.x;
    const int NC  = NCHUNK * TOPK;    // 160 candidates
    __shared__ float mu_s[TOPK];
    __shared__ int   id_s[TOPK];
    if (tid < 64) {
        const unsigned* cp = pc + (size_t)b * NC;
        float v[3]; int ix[3];
        #pragma unroll
        for (int j = 0; j < 3; ++j) {
            const int c  = tid + j * 64;
            const bool ok = c < NC;
            const unsigned u = ok ? cp[c] : 0u;
            v[j]  = ok ? __uint_as_float(u & 0xFFFF0000u) : -3.0e38f;
            ix[j] = ok ? (int)(u & 0xFFFFu) : 0x7fffffff;
        }
        float bv[TOPK]; int bi[TOPK];
        #pragma unroll
        for (int it = 0; it < TOPK; ++it) {
            float m = v[0]; int mi = ix[0];
            if (v[1] > m || (v[1] == m && ix[1] < mi)) { m = v[1]; mi = ix[1]; }
            if (v[2] > m || (v[2] == m && ix[2] < mi)) { m = v[2]; mi = ix[2]; }
            #pragma unroll
            for (int sh = 1; sh < 64; sh <<= 1) {
                const float om = __shfl_xor(m, sh);
                const int   oi = __shfl_xor(mi, sh);
                if (om > m || (om == m && oi < mi)) { m = om; mi = oi; }
            }
            bv[it] = m; bi[it] = mi;
            #pragma unroll
            for (int j = 0; j < 3; ++j) if (ix[j] == mi) v[j] = -3.0e38f;
        }
        if (tid == 0) {
            float ssum = 0.f, w[TOPK];
            #pragma unroll
            for (int j = 0; j < TOPK; ++j) { w[j] = expf(bv[j] - bv[0]); ssum += w[j]; }
            #pragma unroll
            for (int j = 0; j < TOPK; ++j) { mu_s[j] = w[j] / ssum; id_s[j] = bi[j]; }
        }
    }
    __syncthreads();
    const float a = 1.0f / (1.0f + expf(-alpha_p[0]));
    for (int d = tid; d < DIM; d += 256) {
        float r = 0.f;
        #pragma unroll
        for (int j = 0; j < TOPK; ++j) r += mu_s[j] * db[(size_t)id_s[j] * DIM + d];
        out[(size_t)b * DIM + d] = a * h[(size_t)b * DIM + d] + (1.f - a) * r;
    }
}

extern "C" void kernel_launch(void* const* d_in, const int* in_sizes, int n_in,
                              void* d_out, int out_size, void* d_ws, size_t ws_size,
                              hipStream_t stream) {
    const float* h     = (const float*)d_in[0];
    const float* db    = (const float*)d_in[1];
    const float* alpha = (const float*)d_in[2];
    float* out = (float*)d_out;

    const size_t dbz_bytes = (size_t)PADN * DIM * 2;               // 51,380,224
    const size_t hz_bytes  = (size_t)BATCH * DIM * 2;              //  2,097,152
    // packed candidates: 2048 * 32 * 5 * 4 = 1,310,720  -> total 54,788,096

    short*    dbz = (short*)d_ws;
    short*    hz  = (short*)((char*)d_ws + dbz_bytes);
    unsigned* pc  = (unsigned*)((char*)d_ws + dbz_bytes + hz_bytes);

    convert_kernel<PADN><<<PADN / 4, 256, 0, stream>>>(db, dbz, DB_N);
    convert_kernel<BATCH><<<BATCH / 4, 256, 0, stream>>>(h, hz, BATCH);
    sim_topk_kernel<<<8 * NCHUNK, 512, 0, stream>>>(hz, dbz, pc);
    finalize_kernel<<<BATCH, 256, 0, stream>>>(h, db, alpha, pc, out);
}